// Round 2
// 546.897 us; speedup vs baseline: 1.1620x; 1.1620x over previous
//
#include <hip/hip_runtime.h>
#include <math.h>

// Problem constants
#define D_MODEL 512
#define NHEAD   8
#define DH      64
#define D_FF    2048
#define BATCH   16
#define SMAX    512
#define NTOK    (BATCH*SMAX)   // 8192
#define NLAYER  4

constexpr int MODE_QK   = 1;  // bf16 q (pre-scaled 1/8) / k rows [bh][s][64]
constexpr int MODE_VT   = 2;  // bf16 vt [bh][d][s], bias along m
constexpr int MODE_RELU = 3;  // fp8 ff = relu(A*B^T + bias), row-major
constexpr int MODE_PART = 4;  // bf16 partial [z][tok][512]

typedef __attribute__((ext_vector_type(8))) __bf16 bf16x8;
typedef __attribute__((ext_vector_type(4))) float  f32x4;
typedef __attribute__((ext_vector_type(8))) int    i32x8;
typedef unsigned char u8;

#define WSCALE_INV 0.03125f   // weights stored fp8 x32

__device__ __forceinline__ unsigned short f2bf(float f) {
  union { float f; unsigned u; } v; v.f = f;
  unsigned r = v.u + 0x7FFFu + ((v.u >> 16) & 1u);
  return (unsigned short)(r >> 16);
}
__device__ __forceinline__ float bf2f(unsigned short u) {
  union { unsigned u; float f; } v; v.u = ((unsigned)u) << 16; return v.f;
}
// pack 4 floats -> 4 fp8 e4m3 in one int
__device__ __forceinline__ int pk4(float a, float b, float c, float d) {
  int t = __builtin_amdgcn_cvt_pk_fp8_f32(a, b, 0, false);
  t = __builtin_amdgcn_cvt_pk_fp8_f32(c, d, t, true);
  return t;
}

__device__ __forceinline__ void gl_lds16(const unsigned short* g, unsigned short* l) {
  __builtin_amdgcn_global_load_lds(
      (const __attribute__((address_space(1))) unsigned int*)g,
      (__attribute__((address_space(3)))       unsigned int*)l, 16, 0, 0);
}
__device__ __forceinline__ void gl_lds16b(const u8* g, u8* l) {
  __builtin_amdgcn_global_load_lds(
      (const __attribute__((address_space(1))) unsigned int*)g,
      (__attribute__((address_space(3)))       unsigned int*)l, 16, 0, 0);
}

// fp8 BK=128 tile: LDS[row][chunk] (8 chunks of 16B per row), content XOR-
// swizzled on the GLOBAL side: LDS[row][c] = global(row, c ^ (row&7)).
// Reader fetches global chunk c from LDS chunk c ^ (row&7).
__device__ __forceinline__ i32x8 ldfrag(const u8* base, int row, int q) {
  const int rx = row & 7;
  const int4 lo = *(const int4*)(base + (row << 7) + ((((2*q)    ) ^ rx) << 4));
  const int4 hi = *(const int4*)(base + (row << 7) + ((((2*q) + 1) ^ rx) << 4));
  union { int4 p[2]; i32x8 v; } u;
  u.p[0] = lo; u.p[1] = hi;
  return u.v;
}

// ---------------------------------------------------------------------------
// fp8 MX-MFMA GEMM: 128x128 tile, BK=128, 16x16x128 f8f6f4 (unit E8M0 scales
// -> exact fp8 e4m3 math at 2x the non-scaled fp8 MFMA rate).
// 2-stage LDS double buffer (64 KiB -> 2 blocks/CU), counted vmcnt(8).
//   QK/RELU/PART: A=activation (unscaled), B=weight(x32)  -> acc*WSCALE_INV
//   VT:           A=weight(x32),           B=activation   -> acc*WSCALE_INV
// C/D layout of 16x16x128 is identical to 16x16x32 -> epilogues unchanged.
// ---------------------------------------------------------------------------
template<int MODE>
__global__ __launch_bounds__(256)
void gemm_fp8(const u8* __restrict__ A, const u8* __restrict__ Bw,
              const float* __restrict__ bias, u8* __restrict__ C8,
              unsigned short* __restrict__ Cb,
              unsigned short* __restrict__ qd, unsigned short* __restrict__ kd,
              const int* __restrict__ lens, int K, int CK, int N)
{
  const int lin = blockIdx.x + gridDim.x*(blockIdx.y + gridDim.y*blockIdx.z);
  int m0, n0, kz = 0;
  if (MODE == MODE_VT) {
    n0 = (lin % gridDim.x) * 128;
    m0 = (lin / gridDim.x) * 128;
  } else {
    m0 = (lin % gridDim.y) * 128;
    const int rest = lin / gridDim.y;
    n0 = (rest % gridDim.x) * 128;
    kz = rest / gridDim.x;
  }
  if (MODE == MODE_VT) { if ((n0 & 511) >= lens[n0 >> 9]) return; }
  else                 { if ((m0 & 511) >= lens[m0 >> 9]) return; }

  __shared__ __attribute__((aligned(16))) u8 As[2][16384];
  __shared__ __attribute__((aligned(16))) u8 Bs[2][16384];
  const int tid  = threadIdx.x;
  const int lane = tid & 63;
  const int w    = tid >> 6;
  const int wm   = (w & 1) * 64;
  const int wn   = (w >> 1) * 64;
  const int l15  = lane & 15, quad = lane >> 4;

  f32x4 acc[4][4] = {};

  // staging: each thread owns (row = tid>>3 [0..31], chunk = tid&7) per 32-row
  // shot; global source chunk pre-swizzled so LDS dest stays linear.
  const int sr  = tid >> 3;
  const int sch = ((tid & 7) ^ (sr & 7)) * 16;
  const u8* Ag = A  + (long)(m0 + sr) * K + kz*CK + sch;
  const u8* Bg = Bw + (long)(n0 + sr) * K + kz*CK + sch;
  const long rowskip = (long)32 * K;
  const int t16 = tid * 16;
  const int niter = CK >> 7;

  auto stage = [&](int t, int bix) {
    const u8* a_ = Ag + t*128;
    const u8* b_ = Bg + t*128;
#pragma unroll
    for (int s = 0; s < 4; s++) {
      gl_lds16b(a_ + s*rowskip, &As[bix][s*4096 + t16]);
      gl_lds16b(b_ + s*rowskip, &Bs[bix][s*4096 + t16]);
    }
  };

  stage(0, 0);
  stage(1, 1);

  for (int it = 0; it < niter; ++it) {
    if (it + 1 < niter)
      asm volatile("s_waitcnt vmcnt(8)\n\ts_barrier" ::: "memory");
    else
      asm volatile("s_waitcnt vmcnt(0)\n\ts_barrier" ::: "memory");

    const int cur = it & 1;
    const u8* Ac = &As[cur][0];
    const u8* Bc = &Bs[cur][0];

    i32x8 bfv[4];
#pragma unroll
    for (int j = 0; j < 4; j++)
      bfv[j] = ldfrag(Bc, wn + j*16 + l15, quad);
#pragma unroll
    for (int i = 0; i < 4; i++) {
      const i32x8 af = ldfrag(Ac, wm + i*16 + l15, quad);
#pragma unroll
      for (int j = 0; j < 4; j++)
        acc[i][j] = __builtin_amdgcn_mfma_scale_f32_16x16x128_f8f6f4(
            af, bfv[j], acc[i][j], 0, 0, 0, 0x7F7F7F7F, 0, 0x7F7F7F7F);
    }

    if (it + 2 < niter) {
      __syncthreads();            // all waves done reading buf[cur]
      stage(it + 2, cur);
    }
  }

  // ---- epilogue ----
  __syncthreads();
  const int rr8 = lane >> 3, ch8 = lane & 7;

  if (MODE == MODE_RELU) {
    // float bounce -> fp8 pack -> 16B stores
    float* epf = (float*)&As[0][0] + w * 1088;   // 16 rows x 68 floats
#pragma unroll
    for (int i = 0; i < 4; i++) {
#pragma unroll
      for (int j = 0; j < 4; j++) {
        const float cbv = bias[n0 + wn + j*16 + l15];
#pragma unroll
        for (int r = 0; r < 4; r++)
          epf[(quad*4 + r)*68 + j*16 + l15] = fmaxf(acc[i][j][r]*WSCALE_INV + cbv, 0.f);
      }
      asm volatile("s_waitcnt lgkmcnt(0)" ::: "memory");
      const int row = lane >> 2, c16 = (lane & 3) * 16;
      const float* rp = epf + row*68 + c16;
      f32x4 f0 = *(const f32x4*)(rp + 0);
      f32x4 f1 = *(const f32x4*)(rp + 4);
      f32x4 f2 = *(const f32x4*)(rp + 8);
      f32x4 f3 = *(const f32x4*)(rp + 12);
      int4 o;
      o.x = pk4(f0.x, f0.y, f0.z, f0.w);
      o.y = pk4(f1.x, f1.y, f1.z, f1.w);
      o.z = pk4(f2.x, f2.y, f2.z, f2.w);
      o.w = pk4(f3.x, f3.y, f3.z, f3.w);
      const int mrow = m0 + wm + i*16 + row;
      *(int4*)&C8[(long)mrow*N + n0 + wn + c16] = o;
      asm volatile("s_waitcnt lgkmcnt(0)" ::: "memory");
    }
  } else {
    // bf16 bounce (QK / VT / PART)
    unsigned short* epi = (unsigned short*)&As[0][0] + w * 1152;
    const bool isq = (MODE == MODE_QK) && (((n0 + wn) >> 9) == 0);
#pragma unroll
    for (int i = 0; i < 4; i++) {
      float rbv[4];
      if (MODE == MODE_VT) {
#pragma unroll
        for (int r = 0; r < 4; r++) rbv[r] = bias[m0 + wm + i*16 + quad*4 + r];
      }
#pragma unroll
      for (int j = 0; j < 4; j++) {
        float cbv = 0.f;
        if (MODE == MODE_QK) cbv = bias[n0 + wn + j*16 + l15];
#pragma unroll
        for (int r = 0; r < 4; r++) {
          float v = acc[i][j][r] * WSCALE_INV;
          if (MODE == MODE_QK)   { v += cbv; if (isq) v *= 0.125f; }
          if (MODE == MODE_VT)   v += rbv[r];
          epi[(quad*4 + r)*72 + j*16 + l15] = f2bf(v);
        }
      }
      asm volatile("s_waitcnt lgkmcnt(0)" ::: "memory");
#pragma unroll
      for (int rs = 0; rs < 2; rs++) {
        const int row  = rs*8 + rr8;
        const int mrow = m0 + wm + i*16 + row;
        bf16x8 val = *(const bf16x8*)&epi[row*72 + ch8*8];
        if (MODE == MODE_PART) {
          *(bf16x8*)&Cb[((long)kz*NTOK + mrow)*N + n0 + wn + ch8*8] = val;
        } else if (MODE == MODE_QK) {
          const int nb    = n0 + wn;
          const int which = nb >> 9;
          const int head  = (nb >> 6) & 7;
          unsigned short* dst = which ? kd : qd;
          const int bh = (mrow >> 9)*8 + head;
          *(bf16x8*)&dst[((long)(bh*512 + (mrow & 511)))*64 + ch8*8] = val;
        } else {  // MODE_VT
          const int head = mrow >> 6, d = mrow & 63;
          const int tok  = n0 + wn + ch8*8;
          const int b    = tok >> 9;
          *(bf16x8*)&Cb[((long)((b*8 + head)*64 + d))*512 + (tok & 511)] = val;
        }
      }
      asm volatile("s_waitcnt lgkmcnt(0)" ::: "memory");
    }
  }
}

// ---------------------------------------------------------------------------
// Fused split-K reduce + bias + fp8 residual + LayerNorm -> fp8 h.
// ---------------------------------------------------------------------------
template<int KS>
__global__ __launch_bounds__(128)
void reduce_ln(const unsigned short* __restrict__ part,
               const float* __restrict__ bias,
               const float* __restrict__ g, const float* __restrict__ bb,
               u8* __restrict__ h8, const int* __restrict__ lens)
{
  const int row = blockIdx.x, tid = threadIdx.x;
  if ((row & 511) >= lens[row >> 9]) return;
  const int hv = ((const int*)(h8 + (long)row*512))[tid];
  float4 bs = ((const float4*)bias)[tid];
  float v0 = __builtin_amdgcn_cvt_f32_fp8(hv, 0) + bs.x;
  float v1 = __builtin_amdgcn_cvt_f32_fp8(hv, 1) + bs.y;
  float v2 = __builtin_amdgcn_cvt_f32_fp8(hv, 2) + bs.z;
  float v3 = __builtin_amdgcn_cvt_f32_fp8(hv, 3) + bs.w;
#pragma unroll
  for (int z = 0; z < KS; z++) {
    ushort4 p = ((const ushort4*)(part + ((long)z*NTOK + row)*512))[tid];
    v0 += bf2f(p.x); v1 += bf2f(p.y); v2 += bf2f(p.z); v3 += bf2f(p.w);
  }
  float s  = v0 + v1 + v2 + v3;
  float s2 = v0*v0 + v1*v1 + v2*v2 + v3*v3;
#pragma unroll
  for (int off = 1; off < 64; off <<= 1) {
    s  += __shfl_xor(s, off);
    s2 += __shfl_xor(s2, off);
  }
  __shared__ float rb[4];
  if ((tid & 63) == 0) { rb[(tid>>6)*2] = s; rb[(tid>>6)*2+1] = s2; }
  __syncthreads();
  s = rb[0] + rb[2]; s2 = rb[1] + rb[3];
  const float mean = s * (1.f/512.f);
  const float var  = fmaxf(s2 * (1.f/512.f) - mean*mean, 0.f);
  const float rstd = rsqrtf(var + 1e-5f);
  const int e = tid*4;
  const float o0 = (v0-mean)*rstd*g[e+0] + bb[e+0];
  const float o1 = (v1-mean)*rstd*g[e+1] + bb[e+1];
  const float o2 = (v2-mean)*rstd*g[e+2] + bb[e+2];
  const float o3 = (v3-mean)*rstd*g[e+3] + bb[e+3];
  ((int*)(h8 + (long)row*512))[tid] = pk4(o0, o1, o2, o3);
}

// ---------------------------------------------------------------------------
// MFMA flash attention (bf16), grid (bh, qt); ctx output packed fp8.
// ---------------------------------------------------------------------------
__global__ __launch_bounds__(256)
void attn_mfma(const unsigned short* __restrict__ qg,
               const unsigned short* __restrict__ kb,
               const unsigned short* __restrict__ vtb,
               const int* __restrict__ lens,
               u8* __restrict__ ctx8)
{
  const int bh = blockIdx.x, qt = blockIdx.y;
  const int b = bh >> 3, hh = bh & 7;
  const int len = lens[b];
  if (qt*64 >= len) return;

  __shared__ __attribute__((aligned(16))) u8 smem[41984];
  unsigned short* Ks0 = (unsigned short*)smem;              // [2][4096]
  unsigned short* Vts0 = (unsigned short*)(smem + 16384);   // [2][4096]
  unsigned short* Ps  = (unsigned short*)(smem + 32768);    // 4*16*72
  const int tid = threadIdx.x;
  const int w = tid >> 6, lane = tid & 63, l15 = lane & 15, quad = lane >> 4;
  const int t8 = tid * 8;

  const int srow = tid >> 2;
  const int s8   = (tid & 3) * 8;
  const unsigned short* Kbase = kb  + ((long)(bh*512 + srow))*64 + s8;
  const unsigned short* Vbase = vtb + ((long)(bh*64 + srow))*512 + s8;

  const unsigned short* qrow = qg + ((long)(bh*512 + qt*64 + w*16 + l15))*64;
  const bf16x8 qf0 = *(const bf16x8*)(qrow + quad*8);
  const bf16x8 qf1 = *(const bf16x8*)(qrow + 32 + quad*8);

  f32x4 O[4] = {};
  float mrow[4] = {-1e30f,-1e30f,-1e30f,-1e30f};
  float lrow[4] = {0.f,0.f,0.f,0.f};
  unsigned short* Pw = &Ps[w*16*72];
  const int ntiles = (len + 63) >> 6;

  {
    gl_lds16(Kbase,      &Ks0[t8]);
    gl_lds16(Kbase + 32, &Ks0[2048 + t8]);
    gl_lds16(Vbase,      &Vts0[t8]);
    gl_lds16(Vbase + 32, &Vts0[2048 + t8]);
  }

  for (int kt = 0; kt < ntiles; kt++) {
    const int cur = kt & 1;
    unsigned short* Kc  = Ks0  + cur*4096;
    unsigned short* Vc  = Vts0 + cur*4096;
    __syncthreads();
    if (kt + 1 < ntiles) {
      const unsigned short* Kg = Kbase + (long)(kt+1)*64*64;
      const unsigned short* Vg = Vbase + (long)(kt+1)*64;
      unsigned short* Kn = Ks0  + (cur^1)*4096;
      unsigned short* Vn = Vts0 + (cur^1)*4096;
      gl_lds16(Kg,      &Kn[t8]);
      gl_lds16(Kg + 32, &Kn[2048 + t8]);
      gl_lds16(Vg,      &Vn[t8]);
      gl_lds16(Vg + 32, &Vn[2048 + t8]);
    }

    f32x4 sc[4];
#pragma unroll
    for (int ks = 0; ks < 4; ks++) {
      bf16x8 kf0 = *(const bf16x8*)&Kc[       (ks*16 + l15)*32 + quad*8];
      bf16x8 kf1 = *(const bf16x8*)&Kc[2048 + (ks*16 + l15)*32 + quad*8];
      f32x4 z = {};
      z = __builtin_amdgcn_mfma_f32_16x16x32_bf16(qf0, kf0, z, 0, 0, 0);
      sc[ks] = __builtin_amdgcn_mfma_f32_16x16x32_bf16(qf1, kf1, z, 0, 0, 0);
    }

    if (kt*64 + 64 > len) {
#pragma unroll
      for (int ks = 0; ks < 4; ks++) {
        const bool valid = (kt*64 + ks*16 + l15) < len;
#pragma unroll
        for (int r = 0; r < 4; r++)
          sc[ks][r] = valid ? sc[ks][r] : -1e30f;
      }
    }

    float pv[4][4];
#pragma unroll
    for (int r = 0; r < 4; r++) {
      float mx = fmaxf(fmaxf(sc[0][r], sc[1][r]), fmaxf(sc[2][r], sc[3][r]));
      mx = fmaxf(mx, __shfl_xor(mx, 1));
      mx = fmaxf(mx, __shfl_xor(mx, 2));
      mx = fmaxf(mx, __shfl_xor(mx, 4));
      mx = fmaxf(mx, __shfl_xor(mx, 8));
      const float newm  = fmaxf(mrow[r], mx);
      const float alpha = __expf(mrow[r] - newm);
      float ps = 0.f;
#pragma unroll
      for (int ks = 0; ks < 4; ks++) { pv[ks][r] = __expf(sc[ks][r] - newm); ps += pv[ks][r]; }
      ps += __shfl_xor(ps, 1); ps += __shfl_xor(ps, 2);
      ps += __shfl_xor(ps, 4); ps += __shfl_xor(ps, 8);
      lrow[r] = lrow[r]*alpha + ps;
      mrow[r] = newm;
#pragma unroll
      for (int d = 0; d < 4; d++) O[d][r] *= alpha;
    }

#pragma unroll
    for (int ks = 0; ks < 4; ks++)
#pragma unroll
      for (int r = 0; r < 4; r++)
        Pw[(quad*4 + r)*72 + ks*16 + l15] = f2bf(pv[ks][r]);
    asm volatile("s_waitcnt lgkmcnt(0)" ::: "memory");

    const bf16x8 pa0 = *(const bf16x8*)&Pw[l15*72 + quad*8];
    const bf16x8 pa1 = *(const bf16x8*)&Pw[l15*72 + 32 + quad*8];
#pragma unroll
    for (int d = 0; d < 4; d++) {
      bf16x8 vf0 = *(const bf16x8*)&Vc[       (d*16 + l15)*32 + quad*8];
      bf16x8 vf1 = *(const bf16x8*)&Vc[2048 + (d*16 + l15)*32 + quad*8];
      O[d] = __builtin_amdgcn_mfma_f32_16x16x32_bf16(pa0, vf0, O[d], 0, 0, 0);
      O[d] = __builtin_amdgcn_mfma_f32_16x16x32_bf16(pa1, vf1, O[d], 0, 0, 0);
    }
  }

  // ctx: float bounce (reuses Ks/Vts area) -> fp8 pack -> 16B stores
  __syncthreads();
  float* epf = (float*)smem + w * 1088;   // 16 x 68 floats per wave
#pragma unroll
  for (int r = 0; r < 4; r++) {
    const float inv = 1.f / lrow[r];
#pragma unroll
    for (int d = 0; d < 4; d++)
      epf[(quad*4 + r)*68 + d*16 + l15] = O[d][r] * inv;
  }
  asm volatile("s_waitcnt lgkmcnt(0)" ::: "memory");
  {
    const int row = lane >> 2, c16 = (lane & 3) * 16;
    const float* rp = epf + row*68 + c16;
    f32x4 f0 = *(const f32x4*)(rp + 0);
    f32x4 f1 = *(const f32x4*)(rp + 4);
    f32x4 f2 = *(const f32x4*)(rp + 8);
    f32x4 f3 = *(const f32x4*)(rp + 12);
    int4 o;
    o.x = pk4(f0.x, f0.y, f0.z, f0.w);
    o.y = pk4(f1.x, f1.y, f1.z, f1.w);
    o.z = pk4(f2.x, f2.y, f2.z, f2.w);
    o.w = pk4(f3.x, f3.y, f3.z, f3.w);
    const long gaddr = (long)(b*512 + qt*64 + w*16 + row)*512 + hh*64 + c16;
    *(int4*)&ctx8[gaddr] = o;
  }
}

// ---------------------------------------------------------------------------
// PE table (once per launch)
// ---------------------------------------------------------------------------
__global__ __launch_bounds__(256)
void pe_kernel(float* __restrict__ pe)
{
  const int i = blockIdx.x*256 + threadIdx.x;
  const int s = i >> 9, e = i & 511;
  const float dv  = __expf((float)(e & ~1) * (-9.210340371976184f / 512.0f));
  const float ang = (float)s * dv;
  pe[i] = (e & 1) ? cosf(ang) : sinf(ang);
}

// ---------------------------------------------------------------------------
// fp32 embedding GEMM (K=80): h8 = fp8(x*We^T + be + pe[s]).
// ---------------------------------------------------------------------------
__global__ __launch_bounds__(256)
void gemm_embed(const float* __restrict__ A, const float* __restrict__ Bm,
                const float* __restrict__ bias, const float* __restrict__ pe,
                u8* __restrict__ C8, int K, int N)
{
  __shared__ float As[8][132];
  __shared__ float Bs[8][68];
  const int tid = threadIdx.x;
  const int m0 = blockIdx.y * 128;
  const int n0 = blockIdx.x * 64;
  const int tx = tid & 15, ty = tid >> 4;
  const int a_k = tid & 7, a_m = tid >> 3;

  float acc[8][4] = {};
  const float* Ag = A  + (long)(m0 + a_m) * K + a_k;
  const float* Bg = Bm + (long)(n0 + a_m) * K + a_k;

  for (int k0 = 0; k0 < K; k0 += 8) {
#pragma unroll
    for (int i = 0; i < 4; i++)
      As[a_k][a_m + 32*i] = Ag[k0 + (long)32*i*K];
#pragma unroll
    for (int i = 0; i < 2; i++)
      Bs[a_k][a_m + 32*i] = Bg[k0 + (long)32*i*K];
    __syncthreads();
#pragma unroll
    for (int kk = 0; kk < 8; kk++) {
      float a[8], bv[4];
#pragma unroll
      for (int r = 0; r < 8; r++) a[r] = As[kk][ty*8 + r];
#pragma unroll
      for (int c = 0; c < 4; c++) bv[c] = Bs[kk][tx*4 + c];
#pragma unroll
      for (int r = 0; r < 8; r++)
#pragma unroll
        for (int c = 0; c < 4; c++)
          acc[r][c] += a[r] * bv[c];
    }
    __syncthreads();
  }

  const int n_base = n0 + tx*4;
#pragma unroll
  for (int r = 0; r < 8; r++) {
    int m = m0 + ty*8 + r;
    int s = m & 511;
    float4 pv = *(const float4*)(pe + (long)s*512 + n_base);
    int o = pk4(acc[r][0] + bias[n_base+0] + pv.x,
                acc[r][1] + bias[n_base+1] + pv.y,
                acc[r][2] + bias[n_base+2] + pv.z,
                acc[r][3] + bias[n_base+3] + pv.w);
    *(int*)(C8 + (long)m*N + n_base) = o;
  }
}

// fp32 -> fp8 (x32) cast of all 4 weight tensors in one dispatch
#define N4_QKV (NLAYER*3*D_MODEL*D_MODEL/4)
#define N4_WO  (NLAYER*D_MODEL*D_MODEL/4)
#define N4_W1  (NLAYER*D_FF*D_MODEL/4)
#define N4_W2  (NLAYER*D_MODEL*D_FF/4)
__global__ __launch_bounds__(256)
void cvt_all(const float* __restrict__ wq, const float* __restrict__ wo,
             const float* __restrict__ w1, const float* __restrict__ w2,
             u8* __restrict__ oq, u8* __restrict__ oo,
             u8* __restrict__ o1, u8* __restrict__ o2)
{
  int i = blockIdx.x*256 + threadIdx.x;
  const float* src; u8* dst; int off;
  if (i < N4_QKV)                          { src = wq; dst = oq; off = i; }
  else if (i < N4_QKV + N4_WO)             { src = wo; dst = oo; off = i - N4_QKV; }
  else if (i < N4_QKV + N4_WO + N4_W1)     { src = w1; dst = o1; off = i - N4_QKV - N4_WO; }
  else if (i < N4_QKV + N4_WO + N4_W1 + N4_W2) { src = w2; dst = o2; off = i - N4_QKV - N4_WO - N4_W1; }
  else return;
  float4 v = ((const float4*)src)[off];
  ((int*)dst)[off] = pk4(v.x*32.f, v.y*32.f, v.z*32.f, v.w*32.f);
}

__global__ __launch_bounds__(256)
void out_init(float* __restrict__ out, const int* __restrict__ lens)
{
  int i = blockIdx.x*256 + threadIdx.x;
  if (i < 8192) out[i] = 0.f;
  else if (i < 8192 + 16) out[i] = (float)lens[i - 8192];
}

// masked mean pool over fp8 h
__global__ __launch_bounds__(256)
void pool_kernel(const u8* __restrict__ h8,
                 const int* __restrict__ lens, float* __restrict__ out)
{
  const int b = blockIdx.y;
  const int s0 = blockIdx.x * 64;
  const int len = lens[b];
  if (s0 >= len) return;
  const int send = min(s0 + 64, len);
  const int tid = threadIdx.x;
  const int c = (tid & 127) * 4;     // 4 consecutive cols
  const int half = tid >> 7;
  float a0 = 0.f, a1 = 0.f, a2 = 0.f, a3 = 0.f;
  for (int s = s0 + half; s < send; s += 2) {
    const int v = *(const int*)(h8 + ((long)(b*512 + s))*512 + c);
    a0 += __builtin_amdgcn_cvt_f32_fp8(v, 0);
    a1 += __builtin_amdgcn_cvt_f32_fp8(v, 1);
    a2 += __builtin_amdgcn_cvt_f32_fp8(v, 2);
    a3 += __builtin_amdgcn_cvt_f32_fp8(v, 3);
  }
  const float inv = 1.0f / (float)len;
  atomicAdd(out + b*512 + c + 0, a0 * inv);
  atomicAdd(out + b*512 + c + 1, a1 * inv);
  atomicAdd(out + b*512 + c + 2, a2 * inv);
  atomicAdd(out + b*512 + c + 3, a3 * inv);
}

// ---------------------------------------------------------------------------
extern "C" void kernel_launch(void* const* d_in, const int* in_sizes, int n_in,
                              void* d_out, int out_size, void* d_ws, size_t ws_size,
                              hipStream_t stream)
{
  const float* x    = (const float*)d_in[0];
  const int*   lens = (const int*)  d_in[1];
  const float* We   = (const float*)d_in[2];
  const float* be   = (const float*)d_in[3];
  const float* Wqkv = (const float*)d_in[4];
  const float* bqkv = (const float*)d_in[5];
  const float* Wo   = (const float*)d_in[6];
  const float* bo   = (const float*)d_in[7];
  const float* ln1g = (const float*)d_in[8];
  const float* ln1b = (const float*)d_in[9];
  const float* W1   = (const float*)d_in[10];
  const float* b1   = (const float*)d_in[11];
  const float* W2   = (const float*)d_in[12];
  const float* b2   = (const float*)d_in[13];
  const float* ln2g = (const float*)d_in[14];
  const float* ln2b = (const float*)d_in[15];
  float* out = (float*)d_out;

  // Workspace layout (bytes)
  const long TOK_D = (long)NTOK * D_MODEL;              // 4,194,304
  u8* base = (u8*)d_ws;
  float* pe = (float*)base;                             // 1 MB fp32
  u8* h8    = base + 4*TOK_D;                           // fp8 [8192,512]
  u8* ctx8  = h8   + TOK_D;                             // fp8 [8192,512]
  u8* ff8   = ctx8 + TOK_D;                             // fp8 [8192,2048]
  unsigned short* q_b  = (unsigned short*)(ff8 + 4*TOK_D);  // bf16 [bh][s][64]
  unsigned short* k_b  = q_b + TOK_D;
  unsigned short* vt_b = k_b + TOK_D;                   // bf16 [bh][d][s]
  unsigned short* part = vt_b + TOK_D;                  // bf16 [4][8192][512]
  u8* wq8 = (u8*)(part + 4*TOK_D);
  u8* wo8 = wq8 + (long)NLAYER*3*D_MODEL*D_MODEL;
  u8* w18 = wo8 + (long)NLAYER*D_MODEL*D_MODEL;
  u8* w28 = w18 + (long)NLAYER*D_FF*D_MODEL;

  const dim3 blk(256);

  // 0) weight casts (fp8 x32) + PE table
  {
    const int n4tot = N4_QKV + N4_WO + N4_W1 + N4_W2;
    cvt_all<<<dim3((n4tot+255)/256), blk, 0, stream>>>(
        Wqkv, Wo, W1, W2, wq8, wo8, w18, w28);
    pe_kernel<<<dim3(512*512/256), blk, 0, stream>>>(pe);
  }

  // 1) embedding + posenc -> h8 (fp8)
  gemm_embed<<<dim3(D_MODEL/64, NTOK/128), blk, 0, stream>>>(
      x, We, be, pe, h8, 80, D_MODEL);

  for (int l = 0; l < NLAYER; l++) {
    const u8* wq_l = wq8 + (long)l * 3*D_MODEL * D_MODEL;
    const u8* wo_l = wo8 + (long)l * D_MODEL * D_MODEL;
    const u8* w1_l = w18 + (long)l * D_FF * D_MODEL;
    const u8* w2_l = w28 + (long)l * D_MODEL * D_FF;
    const float* bqkv_l = bqkv + (long)l * 3*D_MODEL;
    const float* bo_l   = bo   + (long)l * D_MODEL;
    const float* b1_l   = b1   + (long)l * D_FF;
    const float* b2_l   = b2   + (long)l * D_MODEL;

    // q,k = h*Wqk^T + b -> bf16 [bh][s][64], q pre-scaled 1/8
    gemm_fp8<MODE_QK><<<dim3(2*D_MODEL/128, NTOK/128), blk, 0, stream>>>(
        h8, wq_l, bqkv_l, nullptr, nullptr, q_b, k_b, lens, D_MODEL, D_MODEL, 2*D_MODEL);

    // v^T = Wv*h^T + bv -> bf16 [bh][d][s]
    gemm_fp8<MODE_VT><<<dim3(NTOK/128, D_MODEL/128), blk, 0, stream>>>(
        wq_l + (long)2*D_MODEL*D_MODEL, h8, bqkv_l + 2*D_MODEL, nullptr, vt_b,
        nullptr, nullptr, lens, D_MODEL, D_MODEL, NTOK);

    // attention -> ctx8 (fp8)
    attn_mfma<<<dim3(NHEAD*BATCH, SMAX/64), blk, 0, stream>>>(
        q_b, k_b, vt_b, lens, ctx8);

    // Wo partials (split-K x2) + fused reduce+resid+LN1
    gemm_fp8<MODE_PART><<<dim3(D_MODEL/128, NTOK/128, 2), blk, 0, stream>>>(
        ctx8, wo_l, nullptr, nullptr, part, nullptr, nullptr, lens,
        D_MODEL, D_MODEL/2, D_MODEL);
    reduce_ln<2><<<dim3(NTOK), dim3(128), 0, stream>>>(
        part, bo_l, ln1g + l*D_MODEL, ln1b + l*D_MODEL, h8, lens);

    // ff8 = fp8(relu(h*W1^T + b1))
    gemm_fp8<MODE_RELU><<<dim3(D_FF/128, NTOK/128), blk, 0, stream>>>(
        h8, w1_l, b1_l, ff8, nullptr, nullptr, nullptr, lens, D_MODEL, D_MODEL, D_FF);

    // FF2 partials (split-K x2) + fused reduce+resid+LN2
    gemm_fp8<MODE_PART><<<dim3(D_MODEL/128, NTOK/128, 2), blk, 0, stream>>>(
        ff8, w2_l, nullptr, nullptr, part, nullptr, nullptr, lens,
        D_FF, D_FF/2, D_MODEL);
    reduce_ln<2><<<dim3(NTOK), dim3(128), 0, stream>>>(
        part, b2_l, ln2g + l*D_MODEL, ln2b + l*D_MODEL, h8, lens);
  }

  // 3) masked mean pool + lens output
  out_init<<<dim3((8192 + 16 + 255) / 256), blk, 0, stream>>>(out, lens);
  pool_kernel<<<dim3(SMAX/64, BATCH), blk, 0, stream>>>(h8, lens, out);
}

// Round 3
// 495.261 us; speedup vs baseline: 1.2832x; 1.1043x over previous
//
#include <hip/hip_runtime.h>
#include <math.h>

// Problem constants
#define D_MODEL 512
#define NHEAD   8
#define DH      64
#define D_FF    2048
#define BATCH   16
#define SMAX    512
#define NTOK    (BATCH*SMAX)   // 8192
#define NLAYER  4

constexpr int MODE_QK   = 1;  // bf16 q (pre-scaled) / k rows [bh][s][64]
constexpr int MODE_VT   = 2;  // bf16 vt [bh][d][s], bias along m
constexpr int MODE_RELU = 3;  // fp8 ff = relu(A*B^T + bias), row-major
constexpr int MODE_PART = 4;  // bf16 partial [z][tok][512]

typedef __attribute__((ext_vector_type(8))) __bf16 bf16x8;
typedef __attribute__((ext_vector_type(4))) float  f32x4;
typedef __attribute__((ext_vector_type(8))) int    i32x8;
typedef unsigned char u8;

#define WSCALE_INV 0.03125f   // weights stored fp8 x32
#define QSCALE     0.18033688011112042f   // (1/8) * log2(e): scores in log2 domain

__device__ __forceinline__ unsigned short f2bf(float f) {
  union { float f; unsigned u; } v; v.f = f;
  unsigned r = v.u + 0x7FFFu + ((v.u >> 16) & 1u);
  return (unsigned short)(r >> 16);
}
__device__ __forceinline__ float bf2f(unsigned short u) {
  union { unsigned u; float f; } v; v.u = ((unsigned)u) << 16; return v.f;
}
// pack 4 floats -> 4 fp8 e4m3 in one int
__device__ __forceinline__ int pk4(float a, float b, float c, float d) {
  int t = __builtin_amdgcn_cvt_pk_fp8_f32(a, b, 0, false);
  t = __builtin_amdgcn_cvt_pk_fp8_f32(c, d, t, true);
  return t;
}

__device__ __forceinline__ void gl_lds16(const unsigned short* g, unsigned short* l) {
  __builtin_amdgcn_global_load_lds(
      (const __attribute__((address_space(1))) unsigned int*)g,
      (__attribute__((address_space(3)))       unsigned int*)l, 16, 0, 0);
}
__device__ __forceinline__ void gl_lds16b(const u8* g, u8* l) {
  __builtin_amdgcn_global_load_lds(
      (const __attribute__((address_space(1))) unsigned int*)g,
      (__attribute__((address_space(3)))       unsigned int*)l, 16, 0, 0);
}

// fp8 BK=128 tile: LDS[row][chunk] (8 chunks of 16B per row), content XOR-
// swizzled on the GLOBAL side: LDS[row][c] = global(row, c ^ (row&7)).
__device__ __forceinline__ i32x8 ldfrag(const u8* base, int row, int q) {
  const int rx = row & 7;
  const int4 lo = *(const int4*)(base + (row << 7) + ((((2*q)    ) ^ rx) << 4));
  const int4 hi = *(const int4*)(base + (row << 7) + ((((2*q) + 1) ^ rx) << 4));
  union { int4 p[2]; i32x8 v; } u;
  u.p[0] = lo; u.p[1] = hi;
  return u.v;
}

// ---------------------------------------------------------------------------
// fp8 MX-MFMA GEMM: 128x128 tile, BK=128, 16x16x128 f8f6f4 (unit E8M0 scales
// -> exact fp8 e4m3 math at 2x the non-scaled fp8 MFMA rate).
// ---------------------------------------------------------------------------
template<int MODE>
__global__ __launch_bounds__(256)
void gemm_fp8(const u8* __restrict__ A, const u8* __restrict__ Bw,
              const float* __restrict__ bias, u8* __restrict__ C8,
              unsigned short* __restrict__ Cb,
              unsigned short* __restrict__ qd, unsigned short* __restrict__ kd,
              const int* __restrict__ lens, int K, int CK, int N)
{
  const int lin = blockIdx.x + gridDim.x*(blockIdx.y + gridDim.y*blockIdx.z);
  int m0, n0, kz = 0;
  {
    m0 = (lin % gridDim.y) * 128;
    const int rest = lin / gridDim.y;
    n0 = (rest % gridDim.x) * 128;
    kz = rest / gridDim.x;
  }
  if ((m0 & 511) >= lens[m0 >> 9]) return;

  __shared__ __attribute__((aligned(16))) u8 As[2][16384];
  __shared__ __attribute__((aligned(16))) u8 Bs[2][16384];
  const int tid  = threadIdx.x;
  const int lane = tid & 63;
  const int w    = tid >> 6;
  const int wm   = (w & 1) * 64;
  const int wn   = (w >> 1) * 64;
  const int l15  = lane & 15, quad = lane >> 4;

  f32x4 acc[4][4] = {};

  const int sr  = tid >> 3;
  const int sch = ((tid & 7) ^ (sr & 7)) * 16;
  const u8* Ag = A  + (long)(m0 + sr) * K + kz*CK + sch;
  const u8* Bg = Bw + (long)(n0 + sr) * K + kz*CK + sch;
  const long rowskip = (long)32 * K;
  const int t16 = tid * 16;
  const int niter = CK >> 7;

  auto stage = [&](int t, int bix) {
    const u8* a_ = Ag + t*128;
    const u8* b_ = Bg + t*128;
#pragma unroll
    for (int s = 0; s < 4; s++) {
      gl_lds16b(a_ + s*rowskip, &As[bix][s*4096 + t16]);
      gl_lds16b(b_ + s*rowskip, &Bs[bix][s*4096 + t16]);
    }
  };

  stage(0, 0);
  stage(1, 1);

  for (int it = 0; it < niter; ++it) {
    if (it + 1 < niter)
      asm volatile("s_waitcnt vmcnt(8)\n\ts_barrier" ::: "memory");
    else
      asm volatile("s_waitcnt vmcnt(0)\n\ts_barrier" ::: "memory");

    const int cur = it & 1;
    const u8* Ac = &As[cur][0];
    const u8* Bc = &Bs[cur][0];

    i32x8 bfv[4];
#pragma unroll
    for (int j = 0; j < 4; j++)
      bfv[j] = ldfrag(Bc, wn + j*16 + l15, quad);
#pragma unroll
    for (int i = 0; i < 4; i++) {
      const i32x8 af = ldfrag(Ac, wm + i*16 + l15, quad);
#pragma unroll
      for (int j = 0; j < 4; j++)
        acc[i][j] = __builtin_amdgcn_mfma_scale_f32_16x16x128_f8f6f4(
            af, bfv[j], acc[i][j], 0, 0, 0, 0x7F7F7F7F, 0, 0x7F7F7F7F);
    }

    if (it + 2 < niter) {
      __syncthreads();
      stage(it + 2, cur);
    }
  }

  // ---- epilogue ----
  __syncthreads();
  const int rr8 = lane >> 3, ch8 = lane & 7;

  if (MODE == MODE_RELU) {
    float* epf = (float*)&As[0][0] + w * 1088;   // 16 rows x 68 floats
#pragma unroll
    for (int i = 0; i < 4; i++) {
#pragma unroll
      for (int j = 0; j < 4; j++) {
        const float cbv = bias[n0 + wn + j*16 + l15];
#pragma unroll
        for (int r = 0; r < 4; r++)
          epf[(quad*4 + r)*68 + j*16 + l15] = fmaxf(acc[i][j][r]*WSCALE_INV + cbv, 0.f);
      }
      asm volatile("s_waitcnt lgkmcnt(0)" ::: "memory");
      const int row = lane >> 2, c16 = (lane & 3) * 16;
      const float* rp = epf + row*68 + c16;
      f32x4 f0 = *(const f32x4*)(rp + 0);
      f32x4 f1 = *(const f32x4*)(rp + 4);
      f32x4 f2 = *(const f32x4*)(rp + 8);
      f32x4 f3 = *(const f32x4*)(rp + 12);
      int4 o;
      o.x = pk4(f0.x, f0.y, f0.z, f0.w);
      o.y = pk4(f1.x, f1.y, f1.z, f1.w);
      o.z = pk4(f2.x, f2.y, f2.z, f2.w);
      o.w = pk4(f3.x, f3.y, f3.z, f3.w);
      const int mrow = m0 + wm + i*16 + row;
      *(int4*)&C8[(long)mrow*N + n0 + wn + c16] = o;
      asm volatile("s_waitcnt lgkmcnt(0)" ::: "memory");
    }
  } else {   // MODE_PART
    unsigned short* epi = (unsigned short*)&As[0][0] + w * 1152;
#pragma unroll
    for (int i = 0; i < 4; i++) {
#pragma unroll
      for (int j = 0; j < 4; j++) {
#pragma unroll
        for (int r = 0; r < 4; r++) {
          float v = acc[i][j][r] * WSCALE_INV;
          epi[(quad*4 + r)*72 + j*16 + l15] = f2bf(v);
        }
      }
      asm volatile("s_waitcnt lgkmcnt(0)" ::: "memory");
#pragma unroll
      for (int rs = 0; rs < 2; rs++) {
        const int row  = rs*8 + rr8;
        const int mrow = m0 + wm + i*16 + row;
        bf16x8 val = *(const bf16x8*)&epi[row*72 + ch8*8];
        *(bf16x8*)&Cb[((long)kz*NTOK + mrow)*N + n0 + wn + ch8*8] = val;
      }
      asm volatile("s_waitcnt lgkmcnt(0)" ::: "memory");
    }
  }
}

// ---------------------------------------------------------------------------
// Merged QKV dispatch: blocks 0..511 = QK GEMM (A=h8, B=Wqk), blocks
// 512..767 = VT GEMM (A=Wv, B=h8). Both K=CK=512, niter=4, identical pipeline.
// ---------------------------------------------------------------------------
__global__ __launch_bounds__(256)
void gemm_qkv(const u8* __restrict__ h8, const u8* __restrict__ wq,
              const float* __restrict__ bqkv,
              unsigned short* __restrict__ qd, unsigned short* __restrict__ kd,
              unsigned short* __restrict__ vt_b,
              const int* __restrict__ lens)
{
  const int lin = blockIdx.x;
  const bool isVT = lin >= 512;
  int m0, n0;
  if (isVT) { const int idx = lin - 512; n0 = (idx & 63) * 128; m0 = (idx >> 6) * 128; }
  else      { m0 = (lin & 63) * 128;     n0 = (lin >> 6) * 128; }
  { const int tb = isVT ? n0 : m0;
    if ((tb & 511) >= lens[tb >> 9]) return; }

  const u8* Ap = isVT ? (wq + (long)2*D_MODEL*D_MODEL) : h8;
  const u8* Bp = isVT ? h8 : wq;

  __shared__ __attribute__((aligned(16))) u8 As[2][16384];
  __shared__ __attribute__((aligned(16))) u8 Bs[2][16384];
  const int tid  = threadIdx.x;
  const int lane = tid & 63;
  const int w    = tid >> 6;
  const int wm   = (w & 1) * 64;
  const int wn   = (w >> 1) * 64;
  const int l15  = lane & 15, quad = lane >> 4;

  f32x4 acc[4][4] = {};

  const int sr  = tid >> 3;
  const int sch = ((tid & 7) ^ (sr & 7)) * 16;
  const u8* Ag = Ap + (long)(m0 + sr) * 512 + sch;
  const u8* Bg = Bp + (long)(n0 + sr) * 512 + sch;
  const long rowskip = (long)32 * 512;
  const int t16 = tid * 16;

  auto stage = [&](int t, int bix) {
    const u8* a_ = Ag + t*128;
    const u8* b_ = Bg + t*128;
#pragma unroll
    for (int s = 0; s < 4; s++) {
      gl_lds16b(a_ + s*rowskip, &As[bix][s*4096 + t16]);
      gl_lds16b(b_ + s*rowskip, &Bs[bix][s*4096 + t16]);
    }
  };

  stage(0, 0);
  stage(1, 1);

#pragma unroll 1
  for (int it = 0; it < 4; ++it) {
    if (it + 1 < 4)
      asm volatile("s_waitcnt vmcnt(8)\n\ts_barrier" ::: "memory");
    else
      asm volatile("s_waitcnt vmcnt(0)\n\ts_barrier" ::: "memory");

    const int cur = it & 1;
    const u8* Ac = &As[cur][0];
    const u8* Bc = &Bs[cur][0];

    i32x8 bfv[4];
#pragma unroll
    for (int j = 0; j < 4; j++)
      bfv[j] = ldfrag(Bc, wn + j*16 + l15, quad);
#pragma unroll
    for (int i = 0; i < 4; i++) {
      const i32x8 af = ldfrag(Ac, wm + i*16 + l15, quad);
#pragma unroll
      for (int j = 0; j < 4; j++)
        acc[i][j] = __builtin_amdgcn_mfma_scale_f32_16x16x128_f8f6f4(
            af, bfv[j], acc[i][j], 0, 0, 0, 0x7F7F7F7F, 0, 0x7F7F7F7F);
    }

    if (it + 2 < 4) {
      __syncthreads();
      stage(it + 2, cur);
    }
  }

  // ---- epilogue: bf16 bounce ----
  __syncthreads();
  const int rr8 = lane >> 3, ch8 = lane & 7;
  unsigned short* epi = (unsigned short*)&As[0][0] + w * 1152;
  const bool isq = !isVT && (((n0 + wn) >> 9) == 0);
#pragma unroll
  for (int i = 0; i < 4; i++) {
    float rbv[4];
    if (isVT) {
#pragma unroll
      for (int r = 0; r < 4; r++) rbv[r] = bqkv[2*D_MODEL + m0 + wm + i*16 + quad*4 + r];
    }
#pragma unroll
    for (int j = 0; j < 4; j++) {
      float cbv = 0.f;
      if (!isVT) cbv = bqkv[n0 + wn + j*16 + l15];
#pragma unroll
      for (int r = 0; r < 4; r++) {
        float v = acc[i][j][r] * WSCALE_INV;
        if (!isVT) { v += cbv; if (isq) v *= QSCALE; }
        else       v += rbv[r];
        epi[(quad*4 + r)*72 + j*16 + l15] = f2bf(v);
      }
    }
    asm volatile("s_waitcnt lgkmcnt(0)" ::: "memory");
#pragma unroll
    for (int rs = 0; rs < 2; rs++) {
      const int row  = rs*8 + rr8;
      const int mrow = m0 + wm + i*16 + row;
      bf16x8 val = *(const bf16x8*)&epi[row*72 + ch8*8];
      if (!isVT) {
        const int nb    = n0 + wn;
        const int which = nb >> 9;
        const int head  = (nb >> 6) & 7;
        unsigned short* dst = which ? kd : qd;
        const int bh = (mrow >> 9)*8 + head;
        *(bf16x8*)&dst[((long)(bh*512 + (mrow & 511)))*64 + ch8*8] = val;
      } else {
        const int head = mrow >> 6, d = mrow & 63;
        const int tok  = n0 + wn + ch8*8;
        const int b    = tok >> 9;
        *(bf16x8*)&vt_b[((long)((b*8 + head)*64 + d))*512 + (tok & 511)] = val;
      }
    }
    asm volatile("s_waitcnt lgkmcnt(0)" ::: "memory");
  }
}

// ---------------------------------------------------------------------------
// Fused split-K reduce + bias + fp8 residual + LayerNorm -> fp8 h.
// ---------------------------------------------------------------------------
template<int KS>
__global__ __launch_bounds__(128)
void reduce_ln(const unsigned short* __restrict__ part,
               const float* __restrict__ bias,
               const float* __restrict__ g, const float* __restrict__ bb,
               u8* __restrict__ h8, const int* __restrict__ lens)
{
  const int row = blockIdx.x, tid = threadIdx.x;
  if ((row & 511) >= lens[row >> 9]) return;
  const int hv = ((const int*)(h8 + (long)row*512))[tid];
  float4 bs = ((const float4*)bias)[tid];
  float v0 = __builtin_amdgcn_cvt_f32_fp8(hv, 0) + bs.x;
  float v1 = __builtin_amdgcn_cvt_f32_fp8(hv, 1) + bs.y;
  float v2 = __builtin_amdgcn_cvt_f32_fp8(hv, 2) + bs.z;
  float v3 = __builtin_amdgcn_cvt_f32_fp8(hv, 3) + bs.w;
#pragma unroll
  for (int z = 0; z < KS; z++) {
    ushort4 p = ((const ushort4*)(part + ((long)z*NTOK + row)*512))[tid];
    v0 += bf2f(p.x); v1 += bf2f(p.y); v2 += bf2f(p.z); v3 += bf2f(p.w);
  }
  float s  = v0 + v1 + v2 + v3;
  float s2 = v0*v0 + v1*v1 + v2*v2 + v3*v3;
#pragma unroll
  for (int off = 1; off < 64; off <<= 1) {
    s  += __shfl_xor(s, off);
    s2 += __shfl_xor(s2, off);
  }
  __shared__ float rb[4];
  if ((tid & 63) == 0) { rb[(tid>>6)*2] = s; rb[(tid>>6)*2+1] = s2; }
  __syncthreads();
  s = rb[0] + rb[2]; s2 = rb[1] + rb[3];
  const float mean = s * (1.f/512.f);
  const float var  = fmaxf(s2 * (1.f/512.f) - mean*mean, 0.f);
  const float rstd = rsqrtf(var + 1e-5f);
  const int e = tid*4;
  const float o0 = (v0-mean)*rstd*g[e+0] + bb[e+0];
  const float o1 = (v1-mean)*rstd*g[e+1] + bb[e+1];
  const float o2 = (v2-mean)*rstd*g[e+2] + bb[e+2];
  const float o3 = (v3-mean)*rstd*g[e+3] + bb[e+3];
  ((int*)(h8 + (long)row*512))[tid] = pk4(o0, o1, o2, o3);
}

// ---------------------------------------------------------------------------
// MFMA flash attention (bf16). Scores arrive in log2 domain (q pre-scaled by
// 0.125*log2e). Fixed-shift softmax: p = 2^(s-16) — no online max/rescale
// (scores are LN-bounded, overflow needs s>140). Row-sum reduced once at end.
// ---------------------------------------------------------------------------
__global__ __launch_bounds__(256)
void attn_mfma(const unsigned short* __restrict__ qg,
               const unsigned short* __restrict__ kb,
               const unsigned short* __restrict__ vtb,
               const int* __restrict__ lens,
               u8* __restrict__ ctx8)
{
  const int bh = blockIdx.x, qt = blockIdx.y;
  const int b = bh >> 3, hh = bh & 7;
  const int len = lens[b];
  if (qt*64 >= len) return;

  __shared__ __attribute__((aligned(16))) u8 smem[41984];
  unsigned short* Ks0 = (unsigned short*)smem;              // [2][4096]
  unsigned short* Vts0 = (unsigned short*)(smem + 16384);   // [2][4096]
  unsigned short* Ps  = (unsigned short*)(smem + 32768);    // 4*16*72
  const int tid = threadIdx.x;
  const int w = tid >> 6, lane = tid & 63, l15 = lane & 15, quad = lane >> 4;
  const int t8 = tid * 8;

  const int srow = tid >> 2;
  const int s8   = (tid & 3) * 8;
  const unsigned short* Kbase = kb  + ((long)(bh*512 + srow))*64 + s8;
  const unsigned short* Vbase = vtb + ((long)(bh*64 + srow))*512 + s8;

  const unsigned short* qrow = qg + ((long)(bh*512 + qt*64 + w*16 + l15))*64;
  const bf16x8 qf0 = *(const bf16x8*)(qrow + quad*8);
  const bf16x8 qf1 = *(const bf16x8*)(qrow + 32 + quad*8);

  f32x4 O[4] = {};
  float lrow[4] = {0.f,0.f,0.f,0.f};
  unsigned short* Pw = &Ps[w*16*72];
  const int ntiles = (len + 63) >> 6;

  {
    gl_lds16(Kbase,      &Ks0[t8]);
    gl_lds16(Kbase + 32, &Ks0[2048 + t8]);
    gl_lds16(Vbase,      &Vts0[t8]);
    gl_lds16(Vbase + 32, &Vts0[2048 + t8]);
  }

  for (int kt = 0; kt < ntiles; kt++) {
    const int cur = kt & 1;
    unsigned short* Kc  = Ks0  + cur*4096;
    unsigned short* Vc  = Vts0 + cur*4096;
    __syncthreads();
    if (kt + 1 < ntiles) {
      const unsigned short* Kg = Kbase + (long)(kt+1)*64*64;
      const unsigned short* Vg = Vbase + (long)(kt+1)*64;
      unsigned short* Kn = Ks0  + (cur^1)*4096;
      unsigned short* Vn = Vts0 + (cur^1)*4096;
      gl_lds16(Kg,      &Kn[t8]);
      gl_lds16(Kg + 32, &Kn[2048 + t8]);
      gl_lds16(Vg,      &Vn[t8]);
      gl_lds16(Vg + 32, &Vn[2048 + t8]);
    }

    f32x4 sc[4];
#pragma unroll
    for (int ks = 0; ks < 4; ks++) {
      bf16x8 kf0 = *(const bf16x8*)&Kc[       (ks*16 + l15)*32 + quad*8];
      bf16x8 kf1 = *(const bf16x8*)&Kc[2048 + (ks*16 + l15)*32 + quad*8];
      f32x4 z = {};
      z = __builtin_amdgcn_mfma_f32_16x16x32_bf16(qf0, kf0, z, 0, 0, 0);
      sc[ks] = __builtin_amdgcn_mfma_f32_16x16x32_bf16(qf1, kf1, z, 0, 0, 0);
    }

    if (kt*64 + 64 > len) {
#pragma unroll
      for (int ks = 0; ks < 4; ks++) {
        const bool valid = (kt*64 + ks*16 + l15) < len;
#pragma unroll
        for (int r = 0; r < 4; r++)
          sc[ks][r] = valid ? sc[ks][r] : -1e30f;
      }
    }

    // fixed-shift softmax numerator; per-lane partial row-sums only
    float pv[4][4];
#pragma unroll
    for (int ks = 0; ks < 4; ks++)
#pragma unroll
      for (int r = 0; r < 4; r++) {
        const float p = exp2f(sc[ks][r] - 16.f);
        pv[ks][r] = p;
        lrow[r] += p;
      }

#pragma unroll
    for (int ks = 0; ks < 4; ks++)
#pragma unroll
      for (int r = 0; r < 4; r++)
        Pw[(quad*4 + r)*72 + ks*16 + l15] = f2bf(pv[ks][r]);
    asm volatile("s_waitcnt lgkmcnt(0)" ::: "memory");

    const bf16x8 pa0 = *(const bf16x8*)&Pw[l15*72 + quad*8];
    const bf16x8 pa1 = *(const bf16x8*)&Pw[l15*72 + 32 + quad*8];
#pragma unroll
    for (int d = 0; d < 4; d++) {
      bf16x8 vf0 = *(const bf16x8*)&Vc[       (d*16 + l15)*32 + quad*8];
      bf16x8 vf1 = *(const bf16x8*)&Vc[2048 + (d*16 + l15)*32 + quad*8];
      O[d] = __builtin_amdgcn_mfma_f32_16x16x32_bf16(pa0, vf0, O[d], 0, 0, 0);
      O[d] = __builtin_amdgcn_mfma_f32_16x16x32_bf16(pa1, vf1, O[d], 0, 0, 0);
    }
  }

  // deferred row-sum reduce (within each 16-lane group)
#pragma unroll
  for (int r = 0; r < 4; r++) {
    float t = lrow[r];
    t += __shfl_xor(t, 1);
    t += __shfl_xor(t, 2);
    t += __shfl_xor(t, 4);
    t += __shfl_xor(t, 8);
    lrow[r] = t;
  }

  // ctx: float bounce (reuses Ks/Vts area) -> fp8 pack -> 16B stores
  __syncthreads();
  float* epf = (float*)smem + w * 1088;   // 16 x 68 floats per wave
#pragma unroll
  for (int r = 0; r < 4; r++) {
    const float inv = 1.f / lrow[r];
#pragma unroll
    for (int d = 0; d < 4; d++)
      epf[(quad*4 + r)*68 + d*16 + l15] = O[d][r] * inv;
  }
  asm volatile("s_waitcnt lgkmcnt(0)" ::: "memory");
  {
    const int row = lane >> 2, c16 = (lane & 3) * 16;
    const float* rp = epf + row*68 + c16;
    f32x4 f0 = *(const f32x4*)(rp + 0);
    f32x4 f1 = *(const f32x4*)(rp + 4);
    f32x4 f2 = *(const f32x4*)(rp + 8);
    f32x4 f3 = *(const f32x4*)(rp + 12);
    int4 o;
    o.x = pk4(f0.x, f0.y, f0.z, f0.w);
    o.y = pk4(f1.x, f1.y, f1.z, f1.w);
    o.z = pk4(f2.x, f2.y, f2.z, f2.w);
    o.w = pk4(f3.x, f3.y, f3.z, f3.w);
    const long gaddr = (long)(b*512 + qt*64 + w*16 + row)*512 + hh*64 + c16;
    *(int4*)&ctx8[gaddr] = o;
  }
}

// ---------------------------------------------------------------------------
// fp32 embedding GEMM (K=80): h8 = fp8(x*We^T + be + pe[s]), PE computed
// inline (2 exp2 + 4 sincos per thread) -- no PE table kernel/round-trip.
// ---------------------------------------------------------------------------
__global__ __launch_bounds__(256)
void gemm_embed(const float* __restrict__ A, const float* __restrict__ Bm,
                const float* __restrict__ bias,
                u8* __restrict__ C8, int K, int N)
{
  __shared__ float As[8][132];
  __shared__ float Bs[8][68];
  const int tid = threadIdx.x;
  const int m0 = blockIdx.y * 128;
  const int n0 = blockIdx.x * 64;
  const int tx = tid & 15, ty = tid >> 4;
  const int a_k = tid & 7, a_m = tid >> 3;

  float acc[8][4] = {};
  const float* Ag = A  + (long)(m0 + a_m) * K + a_k;
  const float* Bg = Bm + (long)(n0 + a_m) * K + a_k;

  for (int k0 = 0; k0 < K; k0 += 8) {
#pragma unroll
    for (int i = 0; i < 4; i++)
      As[a_k][a_m + 32*i] = Ag[k0 + (long)32*i*K];
#pragma unroll
    for (int i = 0; i < 2; i++)
      Bs[a_k][a_m + 32*i] = Bg[k0 + (long)32*i*K];
    __syncthreads();
#pragma unroll
    for (int kk = 0; kk < 8; kk++) {
      float a[8], bv[4];
#pragma unroll
      for (int r = 0; r < 8; r++) a[r] = As[kk][ty*8 + r];
#pragma unroll
      for (int c = 0; c < 4; c++) bv[c] = Bs[kk][tx*4 + c];
#pragma unroll
      for (int r = 0; r < 8; r++)
#pragma unroll
        for (int c = 0; c < 4; c++)
          acc[r][c] += a[r] * bv[c];
    }
    __syncthreads();
  }

  const int n_base = n0 + tx*4;
  // pos-enc divisors for the two (sin,cos) pairs in this thread's 4 cols
  const float cfreq = -13.287712379549449f / 512.0f;   // -log2(10000)/512
  const float dv0 = exp2f((float)(n_base)     * cfreq);
  const float dv1 = exp2f((float)(n_base + 2) * cfreq);
#pragma unroll
  for (int r = 0; r < 8; r++) {
    int m = m0 + ty*8 + r;
    int s = m & 511;
    float a0 = (float)s * dv0, a1 = (float)s * dv1;
    float s0v, c0v, s1v, c1v;
    __sincosf(a0, &s0v, &c0v);
    __sincosf(a1, &s1v, &c1v);
    int o = pk4(acc[r][0] + bias[n_base+0] + s0v,
                acc[r][1] + bias[n_base+1] + c0v,
                acc[r][2] + bias[n_base+2] + s1v,
                acc[r][3] + bias[n_base+3] + c1v);
    *(int*)(C8 + (long)m*N + n_base) = o;
  }
}

// fp32 -> fp8 (x32) cast of all 4 weight tensors in one dispatch
#define N4_QKV (NLAYER*3*D_MODEL*D_MODEL/4)
#define N4_WO  (NLAYER*D_MODEL*D_MODEL/4)
#define N4_W1  (NLAYER*D_FF*D_MODEL/4)
#define N4_W2  (NLAYER*D_MODEL*D_FF/4)
__global__ __launch_bounds__(256)
void cvt_all(const float* __restrict__ wq, const float* __restrict__ wo,
             const float* __restrict__ w1, const float* __restrict__ w2,
             u8* __restrict__ oq, u8* __restrict__ oo,
             u8* __restrict__ o1, u8* __restrict__ o2)
{
  int i = blockIdx.x*256 + threadIdx.x;
  const float* src; u8* dst; int off;
  if (i < N4_QKV)                          { src = wq; dst = oq; off = i; }
  else if (i < N4_QKV + N4_WO)             { src = wo; dst = oo; off = i - N4_QKV; }
  else if (i < N4_QKV + N4_WO + N4_W1)     { src = w1; dst = o1; off = i - N4_QKV - N4_WO; }
  else if (i < N4_QKV + N4_WO + N4_W1 + N4_W2) { src = w2; dst = o2; off = i - N4_QKV - N4_WO - N4_W1; }
  else return;
  float4 v = ((const float4*)src)[off];
  ((int*)dst)[off] = pk4(v.x*32.f, v.y*32.f, v.z*32.f, v.w*32.f);
}

__global__ __launch_bounds__(256)
void out_init(float* __restrict__ out, const int* __restrict__ lens)
{
  int i = blockIdx.x*256 + threadIdx.x;
  if (i < 8192) out[i] = 0.f;
  else if (i < 8192 + 16) out[i] = (float)lens[i - 8192];
}

// masked mean pool over fp8 h
__global__ __launch_bounds__(256)
void pool_kernel(const u8* __restrict__ h8,
                 const int* __restrict__ lens, float* __restrict__ out)
{
  const int b = blockIdx.y;
  const int s0 = blockIdx.x * 64;
  const int len = lens[b];
  if (s0 >= len) return;
  const int send = min(s0 + 64, len);
  const int tid = threadIdx.x;
  const int c = (tid & 127) * 4;     // 4 consecutive cols
  const int half = tid >> 7;
  float a0 = 0.f, a1 = 0.f, a2 = 0.f, a3 = 0.f;
  for (int s = s0 + half; s < send; s += 2) {
    const int v = *(const int*)(h8 + ((long)(b*512 + s))*512 + c);
    a0 += __builtin_amdgcn_cvt_f32_fp8(v, 0);
    a1 += __builtin_amdgcn_cvt_f32_fp8(v, 1);
    a2 += __builtin_amdgcn_cvt_f32_fp8(v, 2);
    a3 += __builtin_amdgcn_cvt_f32_fp8(v, 3);
  }
  const float inv = 1.0f / (float)len;
  atomicAdd(out + b*512 + c + 0, a0 * inv);
  atomicAdd(out + b*512 + c + 1, a1 * inv);
  atomicAdd(out + b*512 + c + 2, a2 * inv);
  atomicAdd(out + b*512 + c + 3, a3 * inv);
}

// ---------------------------------------------------------------------------
extern "C" void kernel_launch(void* const* d_in, const int* in_sizes, int n_in,
                              void* d_out, int out_size, void* d_ws, size_t ws_size,
                              hipStream_t stream)
{
  const float* x    = (const float*)d_in[0];
  const int*   lens = (const int*)  d_in[1];
  const float* We   = (const float*)d_in[2];
  const float* be   = (const float*)d_in[3];
  const float* Wqkv = (const float*)d_in[4];
  const float* bqkv = (const float*)d_in[5];
  const float* Wo   = (const float*)d_in[6];
  const float* bo   = (const float*)d_in[7];
  const float* ln1g = (const float*)d_in[8];
  const float* ln1b = (const float*)d_in[9];
  const float* W1   = (const float*)d_in[10];
  const float* b1   = (const float*)d_in[11];
  const float* W2   = (const float*)d_in[12];
  const float* b2   = (const float*)d_in[13];
  const float* ln2g = (const float*)d_in[14];
  const float* ln2b = (const float*)d_in[15];
  float* out = (float*)d_out;

  // Workspace layout (bytes) — pe slot retained for layout stability (unused)
  const long TOK_D = (long)NTOK * D_MODEL;              // 4,194,304
  u8* base = (u8*)d_ws;
  u8* h8    = base + 4*TOK_D;                           // fp8 [8192,512]
  u8* ctx8  = h8   + TOK_D;                             // fp8 [8192,512]
  u8* ff8   = ctx8 + TOK_D;                             // fp8 [8192,2048]
  unsigned short* q_b  = (unsigned short*)(ff8 + 4*TOK_D);  // bf16 [bh][s][64]
  unsigned short* k_b  = q_b + TOK_D;
  unsigned short* vt_b = k_b + TOK_D;                   // bf16 [bh][d][s]
  unsigned short* part = vt_b + TOK_D;                  // bf16 [z][8192][512]
  u8* wq8 = (u8*)(part + 4*TOK_D);
  u8* wo8 = wq8 + (long)NLAYER*3*D_MODEL*D_MODEL;
  u8* w18 = wo8 + (long)NLAYER*D_MODEL*D_MODEL;
  u8* w28 = w18 + (long)NLAYER*D_FF*D_MODEL;

  const dim3 blk(256);

  // 0) weight casts (fp8 x32)
  {
    const int n4tot = N4_QKV + N4_WO + N4_W1 + N4_W2;
    cvt_all<<<dim3((n4tot+255)/256), blk, 0, stream>>>(
        Wqkv, Wo, W1, W2, wq8, wo8, w18, w28);
  }

  // 1) embedding + inline posenc -> h8 (fp8)
  gemm_embed<<<dim3(D_MODEL/64, NTOK/128), blk, 0, stream>>>(
      x, We, be, h8, 80, D_MODEL);

  for (int l = 0; l < NLAYER; l++) {
    const u8* wq_l = wq8 + (long)l * 3*D_MODEL * D_MODEL;
    const u8* wo_l = wo8 + (long)l * D_MODEL * D_MODEL;
    const u8* w1_l = w18 + (long)l * D_FF * D_MODEL;
    const u8* w2_l = w28 + (long)l * D_MODEL * D_FF;
    const float* bqkv_l = bqkv + (long)l * 3*D_MODEL;
    const float* bo_l   = bo   + (long)l * D_MODEL;
    const float* b1_l   = b1   + (long)l * D_FF;
    const float* b2_l   = b2   + (long)l * D_MODEL;

    // q,k,v in one dispatch: q pre-scaled (1/8·log2e); v transposed [bh][d][s]
    gemm_qkv<<<dim3(768), blk, 0, stream>>>(
        h8, wq_l, bqkv_l, q_b, k_b, vt_b, lens);

    // attention -> ctx8 (fp8)
    attn_mfma<<<dim3(NHEAD*BATCH, SMAX/64), blk, 0, stream>>>(
        q_b, k_b, vt_b, lens, ctx8);

    // Wo partials (split-K x2) + fused reduce+resid+LN1
    gemm_fp8<MODE_PART><<<dim3(D_MODEL/128, NTOK/128, 2), blk, 0, stream>>>(
        ctx8, wo_l, nullptr, nullptr, part, nullptr, nullptr, lens,
        D_MODEL, D_MODEL/2, D_MODEL);
    reduce_ln<2><<<dim3(NTOK), dim3(128), 0, stream>>>(
        part, bo_l, ln1g + l*D_MODEL, ln1b + l*D_MODEL, h8, lens);

    // ff8 = fp8(relu(h*W1^T + b1))
    gemm_fp8<MODE_RELU><<<dim3(D_FF/128, NTOK/128), blk, 0, stream>>>(
        h8, w1_l, b1_l, ff8, nullptr, nullptr, nullptr, lens, D_MODEL, D_MODEL, D_FF);

    // FF2 partials (split-K x2) + fused reduce+resid+LN2
    gemm_fp8<MODE_PART><<<dim3(D_MODEL/128, NTOK/128, 2), blk, 0, stream>>>(
        ff8, w2_l, nullptr, nullptr, part, nullptr, nullptr, lens,
        D_FF, D_FF/2, D_MODEL);
    reduce_ln<2><<<dim3(NTOK), dim3(128), 0, stream>>>(
        part, b2_l, ln2g + l*D_MODEL, ln2b + l*D_MODEL, h8, lens);
  }

  // 3) masked mean pool + lens output
  out_init<<<dim3((8192 + 16 + 255) / 256), blk, 0, stream>>>(out, lens);
  pool_kernel<<<dim3(SMAX/64, BATCH), blk, 0, stream>>>(h8, lens, out);
}